// Round 8
// baseline (194.489 us; speedup 1.0000x reference)
//
#include <hip/hip_runtime.h>

typedef __attribute__((ext_vector_type(4))) float f32x4;
typedef __attribute__((ext_vector_type(8))) short short8;
typedef __attribute__((ext_vector_type(4))) unsigned u32x4;

#define DEV __device__ __forceinline__

DEV float fastrcp(float x){ return __builtin_amdgcn_rcpf(x); }
DEV float exp2r(float x){ return __builtin_amdgcn_exp2f(x); }

// ---- trans-minimized LSTM pointwise (common-denominator folding) ----
DEV float lstm_c(float gi, float gf, float gg, float cb){
  float v = exp2r(gi*-1.44269504f);
  float u = exp2r(gf*-1.44269504f);
  float w = exp2r(gg*2.88539008f);
  float pv = 1.f+v, pu = 1.f+u, pw = 1.f+w;
  float pvw = pv*pw;
  return (cb*pvw + (w-1.f)*pu) * fastrcp(pu*pvw);
}
DEV float lstm_h(float go, float c){
  float x = exp2r(go*-1.44269504f);
  float y = exp2r(c*2.88539008f);
  return (y-1.f)*fastrcp((1.f+x)*(1.f+y));
}
DEV float lstm0_c(float gi, float gg){
  float v = exp2r(gi*-1.44269504f);
  float w = exp2r(gg*2.88539008f);
  return (w-1.f)*fastrcp((1.f+v)*(1.f+w));
}

// one-instruction bf16 packing (RNE)
DEV unsigned cvtpk(float lo, float hi){ unsigned r; asm("v_cvt_pk_bf16_f32 %0, %1, %2" : "=v"(r) : "v"(lo), "v"(hi)); return r; }
DEV unsigned short f2bf(float f){ return (unsigned short)cvtpk(f,f); }
DEV float bf2f(unsigned short h){ return __uint_as_float(((unsigned)h)<<16); }
DEV unsigned pack2(float a, float b){ return cvtpk(a,b); }

// bank swizzle for [feat][64batch] bf16 arrays (2-way-free on all hot patterns)
DEV int gmask(int f){ return ((f&1)<<5) | (f&2) | ((f&4)<<2); }
DEV void stBF(char* A, int f, int b, float v){ *(unsigned short*)(A + (((f<<6) + (b ^ gmask(f)))<<1)) = f2bf(v); }
DEV void stBFpair(char* A, int f, int b, float v0, float v1){
  *(unsigned*)(A + (((f<<6) + (b ^ gmask(f)))<<1)) = cvtpk(v0, v1);
}
DEV float ldBF(const char* A, int f, int b){ return bf2f(*(const unsigned short*)(A + (((f<<6) + (b ^ gmask(f)))<<1))); }
DEV float2 ldBF2(const char* A, int f, int b){
  unsigned u = *(const unsigned*)(A + (((f<<6) + (b ^ gmask(f)))<<1));
  return make_float2(__uint_as_float(u<<16), __uint_as_float(u & 0xffff0000u));
}

DEV short8 frag(const char* p){ return *(const short8*)p; }
DEV short8 gfrag(const char* p){ return *(const short8*)p; }   // global B-frag -> VGPR (L2-hit)
DEV f32x4 MF(short8 a, short8 b, f32x4 c){ return __builtin_amdgcn_mfma_f32_16x16x32_bf16(a,b,c,0,0,0); }

struct P {
  const float *spec;
  const float *fw_ih1,*fw_hh1,*fb1,*fw_ih2,*fw_hh2,*fb2,*fw_ih3,*fw_hh3,*fb3,*fw_ih4,*fw_hh4,*fb4;
  const float *bw_ih1,*bw_hh1,*bb1,*bw_ih2,*bw_hh2,*bb2,*bw_ih3,*bw_hh3,*bb3,*bw_ih4,*bw_hh4,*bb4;
  const float *ft12h,*ft12c,*ft23h,*ft23c,*ft34h,*bt43h,*bt43c,*bt32h,*bt32c,*bt21h,*bt21c;
  float *out;
};

// blob offsets in KB; slot = 1KB = one 16(row)x32(k) bf16 B-fragment
#define OF1 0
#define OF2 48
#define OF3 72
#define OF4 80
#define OB4 86
#define OB3 90
#define OB2 98
#define OB1 122
#define BLOBB (194*1024)

// ---------------- prep: pack weights into bf16 B-fragments -----------------
__global__ __launch_bounds__(256) void dsgsf_prep(P p, char* blob){
  int s = blockIdx.x;
  if (s == 3 || s == 4){            // F4 / B4: parity-packed (full 32-k spec chunks)
    bool isF = (s == 3);
    const float* wih = isF ? p.fw_ih4 : p.bw_ih4;
    const float* whh = p.fw_hh4;
    int nslot = isF ? 6 : 4;
    int off   = isF ? OF4 : OB4;
    for (int n = threadIdx.x; n < nslot*64; n += 256){
      int st = n>>6, lx = n&63;
      int R = lx&15, half = R>>3, feat = R&7;
      int k0 = ((lx>>4)<<3);
      unsigned dw[4];
      #pragma unroll
      for (int q=0;q<4;++q){
        float a=0.f, bv=0.f;
        int ka=k0+2*q, kb=ka+1;
        if (isF){
          if (st < 4){
            int pp = st>>1, t = st&1;
            int gi = t*2 + half;                 // t0:[i,f] t1:[g,o]
            int src = gi*8 + feat, base = pp*16;
            if (ka>=base && ka<base+16) a  = wih[src*16 + (ka-base)];
            if (kb>=base && kb<base+16) bv = wih[src*16 + (kb-base)];
          } else {
            int t = st-4; int gi = t*2 + half; int src = gi*8 + feat;
            if (ka<8) a  = whh[src*8+ka];
            if (kb<8) bv = whh[src*8+kb];
          }
        } else {
          int pp = st>>1, t = st&1;
          int gi = (t==0) ? (half? 2:0) : (half? -1:3);   // t0:[i,g] t1:[o,pad]
          if (gi >= 0){
            int src = gi*8 + feat, base = pp*16;
            if (ka>=base && ka<base+16) a  = wih[src*16 + (ka-base)];
            if (kb>=base && kb<base+16) bv = wih[src*16 + (kb-base)];
          }
        }
        dw[q] = pack2(a,bv);
      }
      *(uint4*)(blob + (size_t)(off+st)*1024 + lx*16) = make_uint4(dw[0],dw[1],dw[2],dw[3]);
    }
    return;
  }
  const float* wih=nullptr; const float* whh=nullptr;
  int H=0,NG=0,Kx=0,KXT=0,Kh=0,KT=0,NT=0,off=0,o0=0,o1=1,o2=2,o3=3;
  switch(s){
    case 0: wih=p.fw_ih1;               H=64;NG=3;Kx=128;KXT=4;Kh=0; KT=4;NT=12;off=OF1;o1=2;o2=3; break;
    case 1: wih=p.fw_ih2; whh=p.fw_hh2; H=32;NG=4;Kx=64; KXT=2;Kh=32;KT=3;NT=8; off=OF2; break;
    case 2: wih=p.fw_ih3; whh=p.fw_hh3; H=16;NG=4;Kx=32; KXT=1;Kh=16;KT=2;NT=4; off=OF3; break;
    case 5: wih=p.bw_ih3; whh=p.bw_hh3; H=16;NG=4;Kx=32; KXT=1;Kh=16;KT=2;NT=4; off=OB3; break;
    case 6: wih=p.bw_ih2; whh=p.bw_hh2; H=32;NG=4;Kx=64; KXT=2;Kh=32;KT=3;NT=8; off=OB2; break;
    default:wih=p.bw_ih1; whh=p.bw_hh1; H=64;NG=3;Kx=128;KXT=4;Kh=64;KT=6;NT=12;off=OB1; break;
  }
  int total = KT*NT*64;
  for (int n = threadIdx.x; n < total; n += 256){
    int kt = n/(NT*64); int rem = n - kt*NT*64; int nt = rem>>6; int lx = rem&63;
    int R = nt*16 + (lx&15);
    int gi = R / H; int feat = R - gi*H;
    int og = (gi==0)? o0 : (gi==1)? o1 : (gi==2)? o2 : o3;
    int src = og*H + feat;
    int k0 = kt*32 + ((lx>>4)<<3);
    unsigned dw[4];
    #pragma unroll
    for (int q=0;q<4;++q){
      float a=0.f, b=0.f;
      int ka=k0+2*q, kb=ka+1;
      if (gi < NG){
        if (ka < Kx) a = wih[(size_t)src*Kx + ka];
        else { int kh = ka - KXT*32; if (kh>=0 && kh<Kh) a = whh[(size_t)src*Kh + kh]; }
        if (kb < Kx) b = wih[(size_t)src*Kx + kb];
        else { int kh = kb - KXT*32; if (kh>=0 && kh<Kh) b = whh[(size_t)src*Kh + kh]; }
      }
      dw[q] = pack2(a,b);
    }
    *(uint4*)(blob + (size_t)off*1024 + (size_t)(kt*NT + nt)*1024 + lx*16) =
        make_uint4(dw[0],dw[1],dw[2],dw[3]);
  }
}

// ---------------- GEMM: A-frags in registers, B-frags global->VGPR ----------
template<int NG,int NFT,int KT, class AF>
DEV void gemm_reg(f32x4 (&acc)[2][NG], const char* bstage, int nf, int l, AF af){
  constexpr int NT = NG*NFT;
  #pragma unroll
  for (int kt=0; kt<KT; ++kt){
    short8 a0 = af(kt, 0);
    short8 a1 = af(kt, 1);
    #pragma unroll
    for (int g=0; g<NG; ++g){
      short8 bf = gfrag(bstage + (size_t)(kt*NT + g*NFT + nf)*1024 + l*16);
      acc[0][g] = MF(a0, bf, acc[0][g]);
      acc[1][g] = MF(a1, bf, acc[1][g]);
    }
  }
}

template<int NG>
DEV void binit(f32x4 (&acc)[2][NG], const float* bias, int H, int feat,
               int o0, int o1, int o2, int o3){
  int og[4] = {o0,o1,o2,o3};
  #pragma unroll
  for (int g=0; g<NG; ++g){
    float bv = bias[og[g]*H + feat];
    f32x4 v = {bv,bv,bv,bv};
    acc[0][g]=v; acc[1][g]=v;
  }
}

DEV void pw4(const f32x4 (&acc)[2][4], char* AH, char* AC, const char* BC,
             int arow, int cbrow, int mtp, int l){
  #pragma unroll
  for (int mtI=0;mtI<2;++mtI){
    float hv[4], cv[4];
    int bb = (mtp*2+mtI)*16 + ((l>>4)<<2);
    float2 cb01 = ldBF2(BC, cbrow, bb), cb23 = ldBF2(BC, cbrow, bb+2);
    float cbv[4] = {cb01.x, cb01.y, cb23.x, cb23.y};
    #pragma unroll
    for (int r=0;r<4;++r){
      cv[r] = lstm_c(acc[mtI][0][r], acc[mtI][1][r], acc[mtI][2][r], cbv[r]);
      hv[r] = lstm_h(acc[mtI][3][r], cv[r]);
    }
    stBFpair(AH, arow, bb,   hv[0], hv[1]);
    stBFpair(AH, arow, bb+2, hv[2], hv[3]);
    stBFpair(AC, arow, bb,   cv[0], cv[1]);
    stBFpair(AC, arow, bb+2, cv[2], cv[3]);
  }
}

// ---- trans conv(k3,pad1)+exp, register-rotating reads, weights in log2-domain ----
template<int L,int NO>
DEV void convE1(const char* Ain, int row0, const float* tw, int o0, int b,
                float (&y)[NO], float& s){
  float w0=tw[0]*1.44269504f, w1=tw[1]*1.44269504f, w2=tw[2]*1.44269504f;
  s = 0.f;
  float prev = (o0 >= 1) ? ldBF(Ain, row0+o0-1, b) : 0.f;
  float cur  = ldBF(Ain, row0+o0, b);
  #pragma unroll
  for (int j=0;j<NO;++j){
    int c = o0 + j;
    float nxt;
    if (j < NO-1) nxt = ldBF(Ain, row0+c+1, b);
    else          nxt = (o0+NO < L) ? ldBF(Ain, row0+c+1, b) : 0.f;
    float v = w0*prev + w1*cur + w2*nxt;
    y[j] = exp2r(v); s += y[j];
    prev = cur; cur = nxt;
  }
}
template<int L,int NO>
DEV void convE2(const char* Ain, int row0, const float* tw, int o0, int b,
                float (&y)[NO], float& s){
  float w0=tw[0]*1.44269504f, w1=tw[1]*1.44269504f, w2=tw[2]*1.44269504f;
  s = 0.f;
  float left = (o0 >= 1) ? ldBF(Ain, row0+2*o0-1, b) : 0.f;
  #pragma unroll
  for (int j=0;j<NO;++j){
    int c = 2*(o0+j);
    float mid = ldBF(Ain, row0+c,   b);
    float rgt = ldBF(Ain, row0+c+1, b);
    float v = w0*left + w1*mid + w2*rgt;
    y[j] = exp2r(v); s += y[j];
    left = rgt;
  }
}
// normalized write, A-fragment layout (one 16B store per 8 outputs)
template<int SZ,int NO>
DEV void wrTF(char* TFb, int subBase, int o0, int b, const float (&y)[NO], float inv){
  #pragma unroll
  for (int g8=0; g8<NO/8; ++g8){
    int oo = o0 + g8*8, fl = oo&31;
    char* base = TFb + (size_t)((subBase+(oo>>5))*4+(b>>4))*SZ + ((b&15)+16*(fl>>3))*16;
    unsigned d0=cvtpk(y[g8*8+0]*inv,y[g8*8+1]*inv), d1=cvtpk(y[g8*8+2]*inv,y[g8*8+3]*inv);
    unsigned d2=cvtpk(y[g8*8+4]*inv,y[g8*8+5]*inv), d3=cvtpk(y[g8*8+6]*inv,y[g8*8+7]*inv);
    *(uint4*)base = make_uint4(d0,d1,d2,d3);
  }
}
template<int NO>
DEV void wrBC(char* BCb, int row0, int b, const float (&y)[NO], float inv){
  #pragma unroll
  for (int j=0;j<NO;++j) stBF(BCb, row0+j, b, y[j]*inv);
}

// ---------------- main kernel -----------------
// F chain (waves' F-roles) and B chain interleaved per barrier interval:
// {F1,B4} {T12,T43} {F2,B3} {T23,T32} {F3,B2} {T34,T21} {F4,B1} — 9 barriers.
// Spec A-fragments live in registers (xf[4][2], 32 VGPR) — XP deleted.
__global__ __launch_bounds__(512, 4) void dsgsf_main(P p, const char* blob){
  __shared__ __align__(16) char SM[61440];
  char* AHF = SM;                    // 8K  F-chain h state
  char* ACF = SM + 8192;             // 8K  F-chain c state
  char* AHB = SM + 16384;            // 8K  B-chain h state
  char* ACB = SM + 24576;            // 8K  B-chain c state
  char* BCF = SM + 32768;            // 4K  F trans-c outputs (rows 0-31)
  char* BCB = SM + 36864;            // 8K  B trans-c outputs
  char* TFF = SM + 45056;            // 4K  F trans-h A-frags
  char* TFB = SM + 49152;            // 8K  B trans-h A-frags
  float* PSm = (float*)(SM + 57344); // 4K  softmax psums: rows 0-7 F, 8-15 B

  const int tid = threadIdx.x;
  const int l   = tid & 63;
  const int wu  = __builtin_amdgcn_readfirstlane(tid >> 6);
  const int mtp = wu & 1, z = wu >> 1;
  const long b0 = (long)blockIdx.x * 64;

  // ---- per-lane spec A-fragments (each wave only ever touches mt=mtp*2,+1) ----
  short8 xf[4][2];
  {
    const float* sp0 = p.spec + (b0 + mtp*32 + (l&15))*128 + ((l>>4)<<3);
    #pragma unroll
    for (int mtI=0;mtI<2;++mtI){
      #pragma unroll
      for (int kc=0;kc<4;++kc){
        const float* sp = sp0 + mtI*16*128 + kc*32;
        float4 v0 = *(const float4*)sp;
        float4 v1 = *(const float4*)(sp+4);
        xf[kc][mtI] = __builtin_bit_cast(short8,
          (u32x4){cvtpk(v0.x,v0.y), cvtpk(v0.z,v0.w), cvtpk(v1.x,v1.y), cvtpk(v1.z,v1.w)});
      }
    }
  }
  auto xsel = [&](int kc, int mtI)->short8 {   // kc is wave-uniform runtime
    switch(kc){ case 0: return xf[0][mtI]; case 1: return xf[1][mtI];
                case 2: return xf[2][mtI]; default: return xf[3][mtI]; }
  };

  // ================= I1: F1 + B4 =================
  { // F1: lstm0(spec), gates i,g,o
    f32x4 acc[2][3];
    int feat = z*16 + (l&15);
    binit<3>(acc, p.fb1, 64, feat, 0,2,3,0);
    gemm_reg<3,4,4>(acc, blob + (size_t)OF1*1024, z, l,
                    [&](int kt,int mtI){ return xf[kt][mtI]; });
    #pragma unroll
    for (int mtI=0;mtI<2;++mtI){
      float hv[4], cv[4];
      int bb = (mtp*2+mtI)*16 + ((l>>4)<<2);
      #pragma unroll
      for (int r=0;r<4;++r){
        cv[r] = lstm0_c(acc[mtI][0][r], acc[mtI][1][r]);
        hv[r] = lstm_h(acc[mtI][2][r], cv[r]);
      }
      stBFpair(AHF, feat, bb,   hv[0], hv[1]);
      stBFpair(AHF, feat, bb+2, hv[2], hv[3]);
      stBFpair(ACF, feat, bb,   cv[0], cv[1]);
      stBFpair(ACF, feat, bb+2, cv[2], cv[3]);
    }
  }
  { // B4: lstm0(x4), parity-packed, all-lane epilogue
    f32x4 a4[2][2][2];
    float bv0 = ((l&15)<8) ? p.bb4[l&15] : p.bb4[(l&15)+8];   // i | g
    float bv1 = ((l&15)<8) ? p.bb4[24+(l&15)] : 0.f;          // o | pad
    #pragma unroll
    for (int uu=0;uu<2;++uu)
      #pragma unroll
      for (int mtI=0;mtI<2;++mtI){ a4[uu][mtI][0]=f32x4{bv0,bv0,bv0,bv0}; a4[uu][mtI][1]=f32x4{bv1,bv1,bv1,bv1}; }
    const char* bs = blob + (size_t)OB4*1024;
    short8 A0 = xsel(z,0), A1 = xsel(z,1);
    #pragma unroll
    for (int uu=0;uu<2;++uu){
      short8 bx0 = gfrag(bs + (uu*2+0)*1024 + l*16);
      short8 bx1 = gfrag(bs + (uu*2+1)*1024 + l*16);
      a4[uu][0][0]=MF(A0,bx0,a4[uu][0][0]); a4[uu][0][1]=MF(A0,bx1,a4[uu][0][1]);
      a4[uu][1][0]=MF(A1,bx0,a4[uu][1][0]); a4[uu][1][1]=MF(A1,bx1,a4[uu][1][1]);
    }
    const bool sel = (l&15) < 8;
    const int qe = l&7;
    const int u = z*2 + (sel ? 0 : 1);
    const int f = u*8 + qe;
    #pragma unroll
    for (int mtI=0;mtI<2;++mtI){
      float hv[4], cv[4];
      int bb = (mtp*2+mtI)*16 + ((l>>4)<<2);
      #pragma unroll
      for (int r=0;r<4;++r){
        float s0 = __shfl_xor(a4[0][mtI][0][r],8);
        float s1 = __shfl_xor(a4[1][mtI][0][r],8);
        float s2 = __shfl_xor(a4[1][mtI][1][r],8);
        float iv = sel ? a4[0][mtI][0][r] : s1;
        float gv = sel ? s0 : a4[1][mtI][0][r];
        float ov = sel ? a4[0][mtI][1][r] : s2;
        cv[r] = lstm0_c(iv, gv);
        hv[r] = lstm_h(ov, cv[r]);
      }
      stBFpair(AHB, f, bb,   hv[0], hv[1]);
      stBFpair(AHB, f, bb+2, hv[2], hv[3]);
      stBFpair(ACB, f, bb,   cv[0], cv[1]);
      stBFpair(ACB, f, bb+2, cv[2], cv[3]);
    }
  }
  __syncthreads();

  // ================= I2: T12 (psum) + T43 (local) =================
  {
    float y12[8], s12;
    if (wu<4) convE2<64,8>(AHF, 0, p.ft12h, wu*8, l, y12, s12);
    else      convE2<64,8>(ACF, 0, p.ft12c, (wu-4)*8, l, y12, s12);
    PSm[wu*64+l] = s12;
    { // T43: local sums, no psum sync needed
      float y[16], s;
      if (wu<4){ convE1<16,16>(AHB, wu*16, p.bt43h, 0, l, y, s);
                 wrTF<512,16>(TFB, wu, 0, l, y, fastrcp(s)); }
      else     { convE1<16,16>(ACB, (wu-4)*16, p.bt43c, 0, l, y, s);
                 wrBC<16>(BCB, (wu-4)*16, l, y, fastrcp(s)); }
    }
    __syncthreads();
    float tot = (wu<4) ? PSm[0*64+l]+PSm[1*64+l]+PSm[2*64+l]+PSm[3*64+l]
                       : PSm[4*64+l]+PSm[5*64+l]+PSm[6*64+l]+PSm[7*64+l];
    float inv = fastrcp(tot);
    if (wu<4) wrTF<1024,8>(TFF, 0, wu*8, l, y12, inv);
    else      wrBC<8>(BCF, (wu-4)*8, l, y12, inv);
  }
  __syncthreads();

  // ================= I3: F2 + B3 =================
  {
    f32x4 acc[2][4];
    int step = z>>1, nf = z&1;
    int feat = nf*16 + (l&15);
    binit<4>(acc, p.fb2, 32, feat, 0,1,2,3);
    gemm_reg<4,2,3>(acc, blob + (size_t)OF2*1024, nf, l,
      [&](int kt,int mtI){
        return (kt<2) ? xsel(2*step+kt, mtI)
                      : frag(TFF + (size_t)(mtp*2+mtI)*1024 + l*16); });
    pw4(acc, AHF, ACF, BCF, step*32+feat, feat, mtp, l);
  }
  {
    f32x4 acc[2][4];
    int s = z, feat = l&15;
    binit<4>(acc, p.bb3, 16, feat, 0,1,2,3);
    gemm_reg<4,1,2>(acc, blob + (size_t)OB3*1024, 0, l,
      [&](int kt,int mtI){
        return (kt==0) ? xsel(s, mtI)
                       : frag(TFB + (size_t)((s<<2)+mtp*2+mtI)*512 + (l&31)*16); });
    pw4(acc, AHB, ACB, BCB, s*16+feat, s*16+feat, mtp, l);
  }
  __syncthreads();

  // ================= I4: T23 + T32 (both psum) =================
  {
    float y23[8], s23; int v23=wu&3, st23=v23>>1, ch23=v23&1;
    if (wu<4) convE2<32,8>(AHF, st23*32, p.ft23h, ch23*8, l, y23, s23);
    else      convE2<32,8>(ACF, st23*32, p.ft23c, ch23*8, l, y23, s23);
    PSm[wu*64+l] = s23;
    float y32[16], s32; int st32=(wu&3)>>1, ch32=wu&1;
    if (wu<4) convE1<32,16>(AHB, st32*32, p.bt32h, ch32*16, l, y32, s32);
    else      convE1<32,16>(ACB, st32*32, p.bt32c, ch32*16, l, y32, s32);
    PSm[(8+wu)*64+l] = s32;
    __syncthreads();
    int base = (wu&4) | (st23<<1);
    float inv = fastrcp(PSm[base*64+l] + PSm[(base|1)*64+l]);
    if (wu<4) wrTF<512,8>(TFF, st23, ch23*8, l, y23, inv);
    else      wrBC<8>(BCF, st23*16+ch23*8, l, y23, inv);
    int base2 = 8 + ((wu&4) | (st32<<1));
    float inv2 = fastrcp(PSm[base2*64+l] + PSm[(base2+1)*64+l]);
    if (wu<4) wrTF<1024,16>(TFB, st32, ch32*16, l, y32, inv2);
    else      wrBC<16>(BCB, st32*32+ch32*16, l, y32, inv2);
  }
  __syncthreads();

  // ================= I5: F3 + B2 =================
  {
    f32x4 acc[2][4];
    int s = z, feat = l&15;
    binit<4>(acc, p.fb3, 16, feat, 0,1,2,3);
    gemm_reg<4,1,2>(acc, blob + (size_t)OF3*1024, 0, l,
      [&](int kt,int mtI){
        return (kt==0) ? xsel(s, mtI)
                       : frag(TFF + (size_t)(((s>>1)<<2)+mtp*2+mtI)*512 + (l&31)*16); });
    pw4(acc, AHF, ACF, BCF, s*16+feat, (s>>1)*16+feat, mtp, l);
  }
  {
    f32x4 acc[2][4];
    int t2 = z>>1, nf = z&1;
    int feat = nf*16 + (l&15);
    binit<4>(acc, p.bb2, 32, feat, 0,1,2,3);
    gemm_reg<4,2,3>(acc, blob + (size_t)OB2*1024, nf, l,
      [&](int kt,int mtI){
        return (kt<2) ? xsel(2*t2+kt, mtI)
                      : frag(TFB + (size_t)((t2<<2)+mtp*2+mtI)*1024 + l*16); });
    pw4(acc, AHB, ACB, BCB, t2*32+feat, t2*32+feat, mtp, l);
  }
  __syncthreads();

  // ================= I6: T34 (local) + T21 (psum) =================
  {
    { // T34 local
      float y[8], s;
      if (wu<4){ convE2<16,8>(AHF, wu*16, p.ft34h, 0, l, y, s);
                 wrTF<256,8>(TFF, wu, 0, l, y, fastrcp(s)); }
      else     { convE2<16,8>(ACF, (wu-4)*16, p.ft34h, 0, l, y, s);   // ref bug: ft34h for c
                 wrBC<8>(BCF, (wu-4)*8, l, y, fastrcp(s)); }
    }
    float y21[16], s21;
    if (wu<4) convE1<64,16>(AHB, 0, p.bt21h, wu*16, l, y21, s21);
    else      convE1<64,16>(ACB, 0, p.bt21c, (wu-4)*16, l, y21, s21);
    PSm[(8+wu)*64+l] = s21;
    __syncthreads();
    float tot = (wu<4) ? PSm[8*64+l]+PSm[9*64+l]+PSm[10*64+l]+PSm[11*64+l]
                       : PSm[12*64+l]+PSm[13*64+l]+PSm[14*64+l]+PSm[15*64+l];
    float inv = fastrcp(tot);
    if (wu<4) wrTF<1024,16>(TFB, 0, wu*16, l, y21, inv);
    else      wrBC<16>(BCB, (wu-4)*16, l, y21, inv);
  }
  __syncthreads();

  // ================= I7: F4 + B1 (both write out) =================
  { // F4 (parity-packed, all-lane epilogue)
    f32x4 a4[2][2][2];
    float bv0 = p.fb4[l&15], bv1 = p.fb4[16+(l&15)];
    #pragma unroll
    for (int uu=0;uu<2;++uu)
      #pragma unroll
      for (int mtI=0;mtI<2;++mtI){ a4[uu][mtI][0]=f32x4{bv0,bv0,bv0,bv0}; a4[uu][mtI][1]=f32x4{bv1,bv1,bv1,bv1}; }
    const char* bs = blob + (size_t)OF4*1024;
    short8 A0 = xsel(z,0), A1 = xsel(z,1);
    short8 H0 = frag(TFF + (size_t)((z<<2)+mtp*2  )*256 + (l&15)*16);
    short8 H1 = frag(TFF + (size_t)((z<<2)+mtp*2+1)*256 + (l&15)*16);
    short8 bh0 = gfrag(bs + 4*1024 + l*16);
    short8 bh1 = gfrag(bs + 5*1024 + l*16);
    #pragma unroll
    for (int uu=0;uu<2;++uu){
      short8 bx0 = gfrag(bs + (uu*2+0)*1024 + l*16);
      short8 bx1 = gfrag(bs + (uu*2+1)*1024 + l*16);
      a4[uu][0][0]=MF(A0,bx0,a4[uu][0][0]); a4[uu][0][1]=MF(A0,bx1,a4[uu][0][1]);
      a4[uu][1][0]=MF(A1,bx0,a4[uu][1][0]); a4[uu][1][1]=MF(A1,bx1,a4[uu][1][1]);
      a4[uu][0][0]=MF(H0,bh0,a4[uu][0][0]); a4[uu][0][1]=MF(H0,bh1,a4[uu][0][1]);
      a4[uu][1][0]=MF(H1,bh0,a4[uu][1][0]); a4[uu][1][1]=MF(H1,bh1,a4[uu][1][1]);
    }
    const bool sel = (l&15) < 8;
    const int qe = l&7;
    const int u = z*2 + (sel ? 0 : 1);
    #pragma unroll
    for (int mtI=0;mtI<2;++mtI){
      int bb = (mtp*2+mtI)*16 + ((l>>4)<<2);
      float2 cb01 = ldBF2(BCF, z*8+qe, bb), cb23 = ldBF2(BCF, z*8+qe, bb+2);
      float cbv[4] = {cb01.x, cb01.y, cb23.x, cb23.y};
      #pragma unroll
      for (int r=0;r<4;++r){
        float s00 = __shfl_xor(a4[0][mtI][0][r],8), s10 = __shfl_xor(a4[1][mtI][0][r],8);
        float s01 = __shfl_xor(a4[0][mtI][1][r],8), s11 = __shfl_xor(a4[1][mtI][1][r],8);
        float iv = sel ? a4[0][mtI][0][r] : s10;
        float fv = sel ? s00 : a4[1][mtI][0][r];
        float gv = sel ? a4[0][mtI][1][r] : s11;
        float ov = sel ? s01 : a4[1][mtI][1][r];
        float c = lstm_c(iv, fv, gv, cbv[r]);
        float h = lstm_h(ov, c);
        p.out[(size_t)(b0+bb+r)*128 + u*8 + qe] = h;
      }
    }
  }
  { // B1: gates i,f,g -> c only
    f32x4 acc[2][3];
    int feat = z*16 + (l&15);
    binit<3>(acc, p.bb1, 64, feat, 0,1,2,0);
    gemm_reg<3,4,6>(acc, blob + (size_t)OB1*1024, z, l,
      [&](int kt,int mtI){
        return (kt<4) ? xf[kt][mtI]
                      : frag(TFB + (size_t)(((kt-4)<<2)+mtp*2+mtI)*1024 + l*16); });
    #pragma unroll
    for (int mtI=0;mtI<2;++mtI){
      int bb = (mtp*2+mtI)*16 + ((l>>4)<<2);
      float2 cb01 = ldBF2(BCB, feat, bb), cb23 = ldBF2(BCB, feat, bb+2);
      float cbv[4] = {cb01.x, cb01.y, cb23.x, cb23.y};
      #pragma unroll
      for (int r=0;r<4;++r){
        float c = lstm_c(acc[mtI][0][r], acc[mtI][1][r], acc[mtI][2][r], cbv[r]);
        p.out[(size_t)(b0+bb+r)*128 + 64 + feat] = c;
      }
    }
  }
}

extern "C" void kernel_launch(void* const* d_in, const int* in_sizes, int n_in,
                              void* d_out, int out_size, void* d_ws, size_t ws_size,
                              hipStream_t stream) {
  if (ws_size < (size_t)BLOBB) return;
  P p;
  p.spec   = (const float*)d_in[0];
  p.fw_ih1 = (const float*)d_in[1];  p.fw_hh1 = (const float*)d_in[2];  p.fb1 = (const float*)d_in[3];
  p.fw_ih2 = (const float*)d_in[4];  p.fw_hh2 = (const float*)d_in[5];  p.fb2 = (const float*)d_in[6];
  p.fw_ih3 = (const float*)d_in[7];  p.fw_hh3 = (const float*)d_in[8];  p.fb3 = (const float*)d_in[9];
  p.fw_ih4 = (const float*)d_in[10]; p.fw_hh4 = (const float*)d_in[11]; p.fb4 = (const float*)d_in[12];
  p.bw_ih1 = (const float*)d_in[13]; p.bw_hh1 = (const float*)d_in[14]; p.bb1 = (const float*)d_in[15];
  p.bw_ih2 = (const float*)d_in[16]; p.bw_hh2 = (const float*)d_in[17]; p.bb2 = (const float*)d_in[18];
  p.bw_ih3 = (const float*)d_in[19]; p.bw_hh3 = (const float*)d_in[20]; p.bb3 = (const float*)d_in[21];
  p.bw_ih4 = (const float*)d_in[22]; p.bw_hh4 = (const float*)d_in[23]; p.bb4 = (const float*)d_in[24];
  p.ft12h = (const float*)d_in[25]; p.ft12c = (const float*)d_in[26];
  p.ft23h = (const float*)d_in[27]; p.ft23c = (const float*)d_in[28];
  p.ft34h = (const float*)d_in[29];
  p.bt43h = (const float*)d_in[30]; p.bt43c = (const float*)d_in[31];
  p.bt32h = (const float*)d_in[32]; p.bt32c = (const float*)d_in[33];
  p.bt21h = (const float*)d_in[34]; p.bt21c = (const float*)d_in[35];
  p.out = (float*)d_out;

  char* blob = (char*)d_ws;
  hipLaunchKernelGGL(dsgsf_prep, dim3(8), dim3(256), 0, stream, p, blob);
  int Bn = in_sizes[0] / 128;
  hipLaunchKernelGGL(dsgsf_main, dim3(Bn/64), dim3(512), 0, stream, p, (const char*)blob);
}

// Round 9
// 145.413 us; speedup vs baseline: 1.3375x; 1.3375x over previous
//
#include <hip/hip_runtime.h>

typedef __attribute__((ext_vector_type(4))) float f32x4;
typedef __attribute__((ext_vector_type(8))) short short8;

#define DEV __device__ __forceinline__

DEV float fastrcp(float x){ return __builtin_amdgcn_rcpf(x); }
DEV float exp2r(float x){ return __builtin_amdgcn_exp2f(x); }

// ---- trans-minimized LSTM pointwise (common-denominator folding) ----
DEV float lstm_c(float gi, float gf, float gg, float cb){
  float v = exp2r(gi*-1.44269504f);
  float u = exp2r(gf*-1.44269504f);
  float w = exp2r(gg*2.88539008f);
  float pv = 1.f+v, pu = 1.f+u, pw = 1.f+w;
  float pvw = pv*pw;
  return (cb*pvw + (w-1.f)*pu) * fastrcp(pu*pvw);
}
DEV float lstm_h(float go, float c){
  float x = exp2r(go*-1.44269504f);
  float y = exp2r(c*2.88539008f);
  return (y-1.f)*fastrcp((1.f+x)*(1.f+y));
}
DEV float lstm0_c(float gi, float gg){
  float v = exp2r(gi*-1.44269504f);
  float w = exp2r(gg*2.88539008f);
  return (w-1.f)*fastrcp((1.f+v)*(1.f+w));
}

// one-instruction bf16 packing (RNE)
DEV unsigned cvtpk(float lo, float hi){ unsigned r; asm("v_cvt_pk_bf16_f32 %0, %1, %2" : "=v"(r) : "v"(lo), "v"(hi)); return r; }
DEV unsigned short f2bf(float f){ return (unsigned short)cvtpk(f,f); }
DEV float bf2f(unsigned short h){ return __uint_as_float(((unsigned)h)<<16); }
DEV unsigned pack2(float a, float b){ return cvtpk(a,b); }

// bank swizzle for [feat][64batch] bf16 arrays (2-way-free on all hot patterns)
DEV int gmask(int f){ return ((f&1)<<5) | (f&2) | ((f&4)<<2); }
DEV void stBF(char* A, int f, int b, float v){ *(unsigned short*)(A + (((f<<6) + (b ^ gmask(f)))<<1)) = f2bf(v); }
// paired store: batches b (even) and b+1 — adjacent under swizzle (gmask has no bit0)
DEV void stBFpair(char* A, int f, int b, float v0, float v1){
  *(unsigned*)(A + (((f<<6) + (b ^ gmask(f)))<<1)) = cvtpk(v0, v1);
}
DEV float ldBF(const char* A, int f, int b){ return bf2f(*(const unsigned short*)(A + (((f<<6) + (b ^ gmask(f)))<<1))); }
// paired load: batches b (even), b+1
DEV float2 ldBF2(const char* A, int f, int b){
  unsigned u = *(const unsigned*)(A + (((f<<6) + (b ^ gmask(f)))<<1));
  return make_float2(__uint_as_float(u<<16), __uint_as_float(u & 0xffff0000u));
}

DEV short8 frag(const char* p){ return *(const short8*)p; }
DEV short8 gfrag(const char* p){ return *(const short8*)p; }   // global B-frag -> VGPR (L2-hit)
DEV f32x4 MF(short8 a, short8 b, f32x4 c){ return __builtin_amdgcn_mfma_f32_16x16x32_bf16(a,b,c,0,0,0); }

struct P {
  const float *spec;
  const float *fw_ih1,*fw_hh1,*fb1,*fw_ih2,*fw_hh2,*fb2,*fw_ih3,*fw_hh3,*fb3,*fw_ih4,*fw_hh4,*fb4;
  const float *bw_ih1,*bw_hh1,*bb1,*bw_ih2,*bw_hh2,*bb2,*bw_ih3,*bw_hh3,*bb3,*bw_ih4,*bw_hh4,*bb4;
  const float *ft12h,*ft12c,*ft23h,*ft23c,*ft34h,*bt43h,*bt43c,*bt32h,*bt32c,*bt21h,*bt21c;
  float *out;
};

// blob offsets in KB; slot = 1KB = one 16(row)x32(k) bf16 B-fragment
#define OF1 0
#define OF2 48
#define OF3 72
#define OF4 80
#define OB4 86
#define OB3 90
#define OB2 98
#define OB1 122
#define BLOBB (194*1024)

// ---------------- prep: pack weights into bf16 B-fragments -----------------
__global__ __launch_bounds__(256) void dsgsf_prep(P p, char* blob){
  int s = blockIdx.x;
  if (s == 3 || s == 4){            // F4 / B4: parity-packed (full 32-k spec chunks)
    bool isF = (s == 3);
    const float* wih = isF ? p.fw_ih4 : p.bw_ih4;
    const float* whh = p.fw_hh4;
    int nslot = isF ? 6 : 4;
    int off   = isF ? OF4 : OB4;
    for (int n = threadIdx.x; n < nslot*64; n += 256){
      int st = n>>6, lx = n&63;
      int R = lx&15, half = R>>3, feat = R&7;
      int k0 = ((lx>>4)<<3);
      unsigned dw[4];
      #pragma unroll
      for (int q=0;q<4;++q){
        float a=0.f, bv=0.f;
        int ka=k0+2*q, kb=ka+1;
        if (isF){
          if (st < 4){
            int pp = st>>1, t = st&1;
            int gi = t*2 + half;                 // t0:[i,f] t1:[g,o]
            int src = gi*8 + feat, base = pp*16;
            if (ka>=base && ka<base+16) a  = wih[src*16 + (ka-base)];
            if (kb>=base && kb<base+16) bv = wih[src*16 + (kb-base)];
          } else {
            int t = st-4; int gi = t*2 + half; int src = gi*8 + feat;
            if (ka<8) a  = whh[src*8+ka];
            if (kb<8) bv = whh[src*8+kb];
          }
        } else {
          int pp = st>>1, t = st&1;
          int gi = (t==0) ? (half? 2:0) : (half? -1:3);   // t0:[i,g] t1:[o,pad]
          if (gi >= 0){
            int src = gi*8 + feat, base = pp*16;
            if (ka>=base && ka<base+16) a  = wih[src*16 + (ka-base)];
            if (kb>=base && kb<base+16) bv = wih[src*16 + (kb-base)];
          }
        }
        dw[q] = pack2(a,bv);
      }
      *(uint4*)(blob + (size_t)(off+st)*1024 + lx*16) = make_uint4(dw[0],dw[1],dw[2],dw[3]);
    }
    return;
  }
  const float* wih=nullptr; const float* whh=nullptr;
  int H=0,NG=0,Kx=0,KXT=0,Kh=0,KT=0,NT=0,off=0,o0=0,o1=1,o2=2,o3=3;
  switch(s){
    case 0: wih=p.fw_ih1;               H=64;NG=3;Kx=128;KXT=4;Kh=0; KT=4;NT=12;off=OF1;o1=2;o2=3; break;
    case 1: wih=p.fw_ih2; whh=p.fw_hh2; H=32;NG=4;Kx=64; KXT=2;Kh=32;KT=3;NT=8; off=OF2; break;
    case 2: wih=p.fw_ih3; whh=p.fw_hh3; H=16;NG=4;Kx=32; KXT=1;Kh=16;KT=2;NT=4; off=OF3; break;
    case 5: wih=p.bw_ih3; whh=p.bw_hh3; H=16;NG=4;Kx=32; KXT=1;Kh=16;KT=2;NT=4; off=OB3; break;
    case 6: wih=p.bw_ih2; whh=p.bw_hh2; H=32;NG=4;Kx=64; KXT=2;Kh=32;KT=3;NT=8; off=OB2; break;
    default:wih=p.bw_ih1; whh=p.bw_hh1; H=64;NG=3;Kx=128;KXT=4;Kh=64;KT=6;NT=12;off=OB1; break;
  }
  int total = KT*NT*64;
  for (int n = threadIdx.x; n < total; n += 256){
    int kt = n/(NT*64); int rem = n - kt*NT*64; int nt = rem>>6; int lx = rem&63;
    int R = nt*16 + (lx&15);
    int gi = R / H; int feat = R - gi*H;
    int og = (gi==0)? o0 : (gi==1)? o1 : (gi==2)? o2 : o3;
    int src = og*H + feat;
    int k0 = kt*32 + ((lx>>4)<<3);
    unsigned dw[4];
    #pragma unroll
    for (int q=0;q<4;++q){
      float a=0.f, b=0.f;
      int ka=k0+2*q, kb=ka+1;
      if (gi < NG){
        if (ka < Kx) a = wih[(size_t)src*Kx + ka];
        else { int kh = ka - KXT*32; if (kh>=0 && kh<Kh) a = whh[(size_t)src*Kh + kh]; }
        if (kb < Kx) b = wih[(size_t)src*Kx + kb];
        else { int kh = kb - KXT*32; if (kh>=0 && kh<Kh) b = whh[(size_t)src*Kh + kh]; }
      }
      dw[q] = pack2(a,b);
    }
    *(uint4*)(blob + (size_t)off*1024 + (size_t)(kt*NT + nt)*1024 + lx*16) =
        make_uint4(dw[0],dw[1],dw[2],dw[3]);
  }
}

// ---------------- GEMM: B-fragments direct global->VGPR, no barriers ----------
template<int NG,int NFT,int KT, class AF>
DEV void gemm_reg(f32x4 (&acc)[2][NG], const char* bstage, int nf, int mtp, int l, AF af){
  constexpr int NT = NG*NFT;
  #pragma unroll
  for (int kt=0; kt<KT; ++kt){
    short8 a0 = af(kt, mtp*2);
    short8 a1 = af(kt, mtp*2+1);
    #pragma unroll
    for (int g=0; g<NG; ++g){
      short8 bf = gfrag(bstage + (size_t)(kt*NT + g*NFT + nf)*1024 + l*16);
      acc[0][g] = MF(a0, bf, acc[0][g]);
      acc[1][g] = MF(a1, bf, acc[1][g]);
    }
  }
}

template<int NG>
DEV void binit(f32x4 (&acc)[2][NG], const float* bias, int H, int feat,
               int o0, int o1, int o2, int o3){
  int og[4] = {o0,o1,o2,o3};
  #pragma unroll
  for (int g=0; g<NG; ++g){
    float bv = bias[og[g]*H + feat];
    f32x4 v = {bv,bv,bv,bv};
    acc[0][g]=v; acc[1][g]=v;
  }
}

DEV void pw4(const f32x4 (&acc)[2][4], char* AH, char* AC, const char* BC,
             int arow, int cbrow, int mtp, int l){
  #pragma unroll
  for (int mtI=0;mtI<2;++mtI){
    float hv[4], cv[4];
    int bb = (mtp*2+mtI)*16 + ((l>>4)<<2);
    float2 cb01 = ldBF2(BC, cbrow, bb), cb23 = ldBF2(BC, cbrow, bb+2);
    float cbv[4] = {cb01.x, cb01.y, cb23.x, cb23.y};
    #pragma unroll
    for (int r=0;r<4;++r){
      cv[r] = lstm_c(acc[mtI][0][r], acc[mtI][1][r], acc[mtI][2][r], cbv[r]);
      hv[r] = lstm_h(acc[mtI][3][r], cv[r]);
    }
    stBFpair(AH, arow, bb,   hv[0], hv[1]);
    stBFpair(AH, arow, bb+2, hv[2], hv[3]);
    stBFpair(AC, arow, bb,   cv[0], cv[1]);
    stBFpair(AC, arow, bb+2, cv[2], cv[3]);
  }
}

// ---- trans conv(k3,pad1)+exp, register-rotating reads, weights in log2-domain ----
template<int L,int NO>
DEV void convE1(const char* Ain, int row0, const float* tw, int o0, int b,
                float (&y)[NO], float& s){
  float w0=tw[0]*1.44269504f, w1=tw[1]*1.44269504f, w2=tw[2]*1.44269504f;
  s = 0.f;
  float prev = (o0 >= 1) ? ldBF(Ain, row0+o0-1, b) : 0.f;
  float cur  = ldBF(Ain, row0+o0, b);
  #pragma unroll
  for (int j=0;j<NO;++j){
    int c = o0 + j;
    float nxt;
    if (j < NO-1) nxt = ldBF(Ain, row0+c+1, b);
    else          nxt = (o0+NO < L) ? ldBF(Ain, row0+c+1, b) : 0.f;
    float v = w0*prev + w1*cur + w2*nxt;
    y[j] = exp2r(v); s += y[j];
    prev = cur; cur = nxt;
  }
}
template<int L,int NO>
DEV void convE2(const char* Ain, int row0, const float* tw, int o0, int b,
                float (&y)[NO], float& s){
  float w0=tw[0]*1.44269504f, w1=tw[1]*1.44269504f, w2=tw[2]*1.44269504f;
  s = 0.f;
  float left = (o0 >= 1) ? ldBF(Ain, row0+2*o0-1, b) : 0.f;
  #pragma unroll
  for (int j=0;j<NO;++j){
    int c = 2*(o0+j);
    float mid = ldBF(Ain, row0+c,   b);
    float rgt = ldBF(Ain, row0+c+1, b);
    float v = w0*left + w1*mid + w2*rgt;
    y[j] = exp2r(v); s += y[j];
    left = rgt;
  }
}
// normalized write, A-fragment layout (one 16B store per 8 outputs)
template<int SZ,int NO>
DEV void wrTF(char* TFb, int subBase, int o0, int b, const float (&y)[NO], float inv){
  #pragma unroll
  for (int g8=0; g8<NO/8; ++g8){
    int oo = o0 + g8*8, fl = oo&31;
    char* base = TFb + (size_t)((subBase+(oo>>5))*4+(b>>4))*SZ + ((b&15)+16*(fl>>3))*16;
    unsigned d0=cvtpk(y[g8*8+0]*inv,y[g8*8+1]*inv), d1=cvtpk(y[g8*8+2]*inv,y[g8*8+3]*inv);
    unsigned d2=cvtpk(y[g8*8+4]*inv,y[g8*8+5]*inv), d3=cvtpk(y[g8*8+6]*inv,y[g8*8+7]*inv);
    *(uint4*)base = make_uint4(d0,d1,d2,d3);
  }
}
template<int NO>
DEV void wrBC(char* BCb, int row0, int b, const float (&y)[NO], float inv){
  #pragma unroll
  for (int j=0;j<NO;++j) stBF(BCb, row0+j, b, y[j]*inv);
}

// ---------------- main kernel -----------------
// launch_bounds(512,4): VGPR cap 128 (R3: (512,6) -> 40 VGPR + massive spill).
// NOTE (R8 lesson): do NOT hold spec A-frags in a register array indexed by a
// runtime kc — LLVM lowers the selection to a dynamically-indexed local array
// -> scratch spill (rule #20; R8: VGPR 56, WRITE 196MB, 194us). Spec stays in LDS.
__global__ __launch_bounds__(512, 4) void dsgsf_main(P p, const char* blob){
  __shared__ __align__(16) char SM[51200];
  char* XP = SM;               // 16KB: spec A-frags [kc*4+mt]
  char* AH = SM + 16384;       //  8KB: h state [feat][batch] bf16 swizzled
  char* AC = SM + 24576;       //  8KB: c state
  char* BC = SM + 32768;       //  8KB: trans-c outputs
  char* TF = SM + 40960;       //  8KB: trans-h outputs as A-frags
  float* PSm = (float*)(SM + 49152);  // 2KB: softmax partial sums [task][batch]

  const int tid = threadIdx.x;
  const int l   = tid & 63;
  const int wu  = __builtin_amdgcn_readfirstlane(tid >> 6);
  const int mtp = wu & 1, z = wu >> 1;
  const long b0 = (long)blockIdx.x * 64;

  // ---- stage spec into A-fragment layout ----
  #pragma unroll
  for (int it=0; it<2; ++it){
    int n = it*512 + tid; int slot = n>>6, lx = n&63;
    int kc = slot>>2, mt = slot&3;
    const float* sp = p.spec + (b0 + mt*16 + (lx&15))*128 + kc*32 + ((lx>>4)<<3);
    float4 v0 = *(const float4*)sp; float4 v1 = *(const float4*)(sp+4);
    unsigned d0=cvtpk(v0.x,v0.y), d1=cvtpk(v0.z,v0.w);
    unsigned d2=cvtpk(v1.x,v1.y), d3=cvtpk(v1.z,v1.w);
    *(uint4*)(XP + (size_t)slot*1024 + lx*16) = make_uint4(d0,d1,d2,d3);
  }
  __syncthreads();

  // ================= F1: lstm0(spec), gates i,g,o =================
  {
    f32x4 acc[2][3];
    int feat = z*16 + (l&15);
    binit<3>(acc, p.fb1, 64, feat, 0,2,3,0);
    auto af = [&](int kt, int mt){ return frag(XP + (size_t)((kt<<2)+mt)*1024 + l*16); };
    gemm_reg<3,4,4>(acc, blob + (size_t)OF1*1024, z, mtp, l, af);
    #pragma unroll
    for (int mtI=0;mtI<2;++mtI){
      float hv[4], cv[4];
      int bb = (mtp*2+mtI)*16 + ((l>>4)<<2);
      #pragma unroll
      for (int r=0;r<4;++r){
        cv[r] = lstm0_c(acc[mtI][0][r], acc[mtI][1][r]);
        hv[r] = lstm_h(acc[mtI][2][r], cv[r]);
      }
      stBFpair(AH, feat, bb,   hv[0], hv[1]);
      stBFpair(AH, feat, bb+2, hv[2], hv[3]);
      stBFpair(AC, feat, bb,   cv[0], cv[1]);
      stBFpair(AC, feat, bb+2, cv[2], cv[3]);
    }
  }
  __syncthreads();

  // ---- T12: chunks of 8, psum over 4 ----
  {
    float y[8], s;
    if (wu<4) convE2<64,8>(AH, 0, p.ft12h, wu*8, l, y, s);
    else      convE2<64,8>(AC, 0, p.ft12c, (wu-4)*8, l, y, s);
    PSm[wu*64+l] = s;
    __syncthreads();
    float tot = (wu<4) ? PSm[0*64+l]+PSm[1*64+l]+PSm[2*64+l]+PSm[3*64+l]
                       : PSm[4*64+l]+PSm[5*64+l]+PSm[6*64+l]+PSm[7*64+l];
    float inv = fastrcp(tot);
    if (wu<4) wrTF<1024,8>(TF, 0, wu*8, l, y, inv);
    else      wrBC<8>(BC, (wu-4)*8, l, y, inv);
  }
  __syncthreads();

  // ================= F2 =================
  {
    f32x4 acc[2][4];
    int step = z>>1, nf = z&1;
    int feat = nf*16 + (l&15);
    binit<4>(acc, p.fb2, 32, feat, 0,1,2,3);
    auto af = [&](int kt, int mt){
      return (kt<2) ? frag(XP + (size_t)(((2*step+kt)<<2)+mt)*1024 + l*16)
                    : frag(TF + (size_t)mt*1024 + l*16); };
    gemm_reg<4,2,3>(acc, blob + (size_t)OF2*1024, nf, mtp, l, af);
    pw4(acc, AH, AC, BC, step*32+feat, feat, mtp, l);
  }
  __syncthreads();

  // ---- T23: 2 steps x 2 chunks of 8, psum pairs ----
  {
    float y[8], s; int v=wu&3, st=v>>1, ch=v&1;
    if (wu<4) convE2<32,8>(AH, st*32, p.ft23h, ch*8, l, y, s);
    else      convE2<32,8>(AC, st*32, p.ft23c, ch*8, l, y, s);
    PSm[wu*64+l] = s;
    __syncthreads();
    int base = (wu&4) | (st<<1);
    float inv = fastrcp(PSm[base*64+l] + PSm[(base|1)*64+l]);
    if (wu<4) wrTF<512,8>(TF, st, ch*8, l, y, inv);
    else      wrBC<8>(BC, st*16+ch*8, l, y, inv);
  }
  __syncthreads();

  // ================= F3 =================
  {
    f32x4 acc[2][4];
    int s = z, feat = l&15;
    binit<4>(acc, p.fb3, 16, feat, 0,1,2,3);
    auto af = [&](int kt, int mt){
      return (kt==0) ? frag(XP + (size_t)((s<<2)+mt)*1024 + l*16)
                     : frag(TF + (size_t)(((s>>1)<<2)+mt)*512 + (l&31)*16); };
    gemm_reg<4,1,2>(acc, blob + (size_t)OF3*1024, 0, mtp, l, af);
    pw4(acc, AH, AC, BC, s*16+feat, (s>>1)*16+feat, mtp, l);
  }
  __syncthreads();

  // ---- T34: 8 independent rows of 8, local sums ----
  {
    float y[8], s;
    if (wu<4){ convE2<16,8>(AH, wu*16, p.ft34h, 0, l, y, s);
               wrTF<256,8>(TF, wu, 0, l, y, fastrcp(s)); }
    else     { convE2<16,8>(AC, (wu-4)*16, p.ft34h, 0, l, y, s);   // ref bug: ft34h for c
               wrBC<8>(BC, (wu-4)*8, l, y, fastrcp(s)); }
  }
  __syncthreads();

  // ================= F4 (parity-packed, all-lane epilogue) =================
  {
    f32x4 a4[2][2][2]; // [parity uu][mtI][tile]
    float bv0 = p.fb4[l&15], bv1 = p.fb4[16+(l&15)];
    #pragma unroll
    for (int uu=0;uu<2;++uu)
      #pragma unroll
      for (int mtI=0;mtI<2;++mtI){ a4[uu][mtI][0]=f32x4{bv0,bv0,bv0,bv0}; a4[uu][mtI][1]=f32x4{bv1,bv1,bv1,bv1}; }
    const char* bs = blob + (size_t)OF4*1024;
    short8 A0 = frag(XP + (size_t)((z<<2)+mtp*2  )*1024 + l*16);
    short8 A1 = frag(XP + (size_t)((z<<2)+mtp*2+1)*1024 + l*16);
    short8 H0 = frag(TF + (size_t)((z<<2)+mtp*2  )*256 + (l&15)*16);
    short8 H1 = frag(TF + (size_t)((z<<2)+mtp*2+1)*256 + (l&15)*16);
    short8 bh0 = gfrag(bs + 4*1024 + l*16);
    short8 bh1 = gfrag(bs + 5*1024 + l*16);
    #pragma unroll
    for (int uu=0;uu<2;++uu){
      short8 bx0 = gfrag(bs + (uu*2+0)*1024 + l*16);
      short8 bx1 = gfrag(bs + (uu*2+1)*1024 + l*16);
      a4[uu][0][0]=MF(A0,bx0,a4[uu][0][0]); a4[uu][0][1]=MF(A0,bx1,a4[uu][0][1]);
      a4[uu][1][0]=MF(A1,bx0,a4[uu][1][0]); a4[uu][1][1]=MF(A1,bx1,a4[uu][1][1]);
      a4[uu][0][0]=MF(H0,bh0,a4[uu][0][0]); a4[uu][0][1]=MF(H0,bh1,a4[uu][0][1]);
      a4[uu][1][0]=MF(H1,bh0,a4[uu][1][0]); a4[uu][1][1]=MF(H1,bh1,a4[uu][1][1]);
    }
    // lane-half q<8 -> uu=0, q>=8 -> uu=1; gates redistributed by shfl_xor(8)
    const bool sel = (l&15) < 8;
    const int qe = l&7;
    const int u = z*2 + (sel ? 0 : 1);
    #pragma unroll
    for (int mtI=0;mtI<2;++mtI){
      int bb = (mtp*2+mtI)*16 + ((l>>4)<<2);
      float2 cb01 = ldBF2(BC, z*8+qe, bb), cb23 = ldBF2(BC, z*8+qe, bb+2);
      float cbv[4] = {cb01.x, cb01.y, cb23.x, cb23.y};
      #pragma unroll
      for (int r=0;r<4;++r){
        float s00 = __shfl_xor(a4[0][mtI][0][r],8), s10 = __shfl_xor(a4[1][mtI][0][r],8);
        float s01 = __shfl_xor(a4[0][mtI][1][r],8), s11 = __shfl_xor(a4[1][mtI][1][r],8);
        float iv = sel ? a4[0][mtI][0][r] : s10;
        float fv = sel ? s00 : a4[1][mtI][0][r];
        float gv = sel ? a4[0][mtI][1][r] : s11;
        float ov = sel ? s01 : a4[1][mtI][1][r];
        float c = lstm_c(iv, fv, gv, cbv[r]);
        float h = lstm_h(ov, c);
        p.out[(size_t)(b0+bb+r)*128 + u*8 + qe] = h;
      }
    }
  }

  // ================= B4 (parity-packed lstm0, all-lane epilogue) =================
  {
    f32x4 a4[2][2][2];
    float bv0 = ((l&15)<8) ? p.bb4[l&15] : p.bb4[(l&15)+8];   // i | g
    float bv1 = ((l&15)<8) ? p.bb4[24+(l&15)] : 0.f;          // o | pad
    #pragma unroll
    for (int uu=0;uu<2;++uu)
      #pragma unroll
      for (int mtI=0;mtI<2;++mtI){ a4[uu][mtI][0]=f32x4{bv0,bv0,bv0,bv0}; a4[uu][mtI][1]=f32x4{bv1,bv1,bv1,bv1}; }
    const char* bs = blob + (size_t)OB4*1024;
    short8 A0 = frag(XP + (size_t)((z<<2)+mtp*2  )*1024 + l*16);
    short8 A1 = frag(XP + (size_t)((z<<2)+mtp*2+1)*1024 + l*16);
    #pragma unroll
    for (int uu=0;uu<2;++uu){
      short8 bx0 = gfrag(bs + (uu*2+0)*1024 + l*16);
      short8 bx1 = gfrag(bs + (uu*2+1)*1024 + l*16);
      a4[uu][0][0]=MF(A0,bx0,a4[uu][0][0]); a4[uu][0][1]=MF(A0,bx1,a4[uu][0][1]);
      a4[uu][1][0]=MF(A1,bx0,a4[uu][1][0]); a4[uu][1][1]=MF(A1,bx1,a4[uu][1][1]);
    }
    const bool sel = (l&15) < 8;
    const int qe = l&7;
    const int u = z*2 + (sel ? 0 : 1);
    const int f = u*8 + qe;
    #pragma unroll
    for (int mtI=0;mtI<2;++mtI){
      float hv[4], cv[4];
      int bb = (mtp*2+mtI)*16 + ((l>>4)<<2);
      #pragma unroll
      for (int r=0;r<4;++r){
        float s0 = __shfl_xor(a4[0][mtI][0][r],8);   // lane<8 gets g(uu0); lane>=8 gets i(uu0) (unused)
        float s1 = __shfl_xor(a4[1][mtI][0][r],8);   // lane>=8 gets i(uu1)
        float s2 = __shfl_xor(a4[1][mtI][1][r],8);   // lane>=8 gets o(uu1)
        float iv = sel ? a4[0][mtI][0][r] : s1;
        float gv = sel ? s0 : a4[1][mtI][0][r];
        float ov = sel ? a4[0][mtI][1][r] : s2;
        cv[r] = lstm0_c(iv, gv);
        hv[r] = lstm_h(ov, cv[r]);
      }
      stBFpair(AH, f, bb,   hv[0], hv[1]);
      stBFpair(AH, f, bb+2, hv[2], hv[3]);
      stBFpair(AC, f, bb,   cv[0], cv[1]);
      stBFpair(AC, f, bb+2, cv[2], cv[3]);
    }
  }
  __syncthreads();

  // ---- T43: 8 independent rows of 16, local sums ----
  {
    float y[16], s;
    if (wu<4){ convE1<16,16>(AH, wu*16, p.bt43h, 0, l, y, s);
               wrTF<512,16>(TF, wu, 0, l, y, fastrcp(s)); }
    else     { convE1<16,16>(AC, (wu-4)*16, p.bt43c, 0, l, y, s);
               wrBC<16>(BC, (wu-4)*16, l, y, fastrcp(s)); }
  }
  __syncthreads();

  // ================= B3 =================
  {
    f32x4 acc[2][4];
    int s = z, feat = l&15;
    binit<4>(acc, p.bb3, 16, feat, 0,1,2,3);
    auto af = [&](int kt, int mt){
      return (kt==0) ? frag(XP + (size_t)((s<<2)+mt)*1024 + l*16)
                     : frag(TF + (size_t)((s<<2)+mt)*512 + (l&31)*16); };
    gemm_reg<4,1,2>(acc, blob + (size_t)OB3*1024, 0, mtp, l, af);
    pw4(acc, AH, AC, BC, s*16+feat, s*16+feat, mtp, l);
  }
  __syncthreads();

  // ---- T32: 2 steps x 2 chunks of 16, psum pairs ----
  {
    float y[16], s; int v=wu&3, st=v>>1, ch=v&1;
    if (wu<4) convE1<32,16>(AH, st*32, p.bt32h, ch*16, l, y, s);
    else      convE1<32,16>(AC, st*32, p.bt32c, ch*16, l, y, s);
    PSm[wu*64+l] = s;
    __syncthreads();
    int base = (wu&4) | (st<<1);
    float inv = fastrcp(PSm[base*64+l] + PSm[(base|1)*64+l]);
    if (wu<4) wrTF<1024,16>(TF, st, ch*16, l, y, inv);
    else      wrBC<16>(BC, st*32+ch*16, l, y, inv);
  }
  __syncthreads();

  // ================= B2 =================
  {
    f32x4 acc[2][4];
    int t2 = z>>1, nf = z&1;
    int feat = nf*16 + (l&15);
    binit<4>(acc, p.bb2, 32, feat, 0,1,2,3);
    auto af = [&](int kt, int mt){
      return (kt<2) ? frag(XP + (size_t)(((2*t2+kt)<<2)+mt)*1024 + l*16)
                    : frag(TF + (size_t)((t2<<2)+mt)*1024 + l*16); };
    gemm_reg<4,2,3>(acc, blob + (size_t)OB2*1024, nf, mtp, l, af);
    pw4(acc, AH, AC, BC, t2*32+feat, t2*32+feat, mtp, l);
  }
  __syncthreads();

  // ---- T21: 4 chunks of 16, psum over 4 ----
  {
    float y[16], s;
    if (wu<4) convE1<64,16>(AH, 0, p.bt21h, wu*16, l, y, s);
    else      convE1<64,16>(AC, 0, p.bt21c, (wu-4)*16, l, y, s);
    PSm[wu*64+l] = s;
    __syncthreads();
    float tot = (wu<4) ? PSm[0*64+l]+PSm[1*64+l]+PSm[2*64+l]+PSm[3*64+l]
                       : PSm[4*64+l]+PSm[5*64+l]+PSm[6*64+l]+PSm[7*64+l];
    float inv = fastrcp(tot);
    if (wu<4) wrTF<1024,16>(TF, 0, wu*16, l, y, inv);
    else      wrBC<16>(BC, (wu-4)*16, l, y, inv);
  }
  __syncthreads();

  // ================= B1: gates i,f,g -> c only =================
  {
    f32x4 acc[2][3];
    int feat = z*16 + (l&15);
    binit<3>(acc, p.bb1, 64, feat, 0,1,2,0);
    auto af = [&](int kt, int mt){
      return (kt<4) ? frag(XP + (size_t)((kt<<2)+mt)*1024 + l*16)
                    : frag(TF + (size_t)(((kt-4)<<2)+mt)*1024 + l*16); };
    gemm_reg<3,4,6>(acc, blob + (size_t)OB1*1024, z, mtp, l, af);
    #pragma unroll
    for (int mtI=0;mtI<2;++mtI){
      int bb = (mtp*2+mtI)*16 + ((l>>4)<<2);
      float2 cb01 = ldBF2(BC, feat, bb), cb23 = ldBF2(BC, feat, bb+2);
      float cbv[4] = {cb01.x, cb01.y, cb23.x, cb23.y};
      #pragma unroll
      for (int r=0;r<4;++r){
        float c = lstm_c(acc[mtI][0][r], acc[mtI][1][r], acc[mtI][2][r], cbv[r]);
        p.out[(size_t)(b0+bb+r)*128 + 64 + feat] = c;
      }
    }
  }
}

extern "C" void kernel_launch(void* const* d_in, const int* in_sizes, int n_in,
                              void* d_out, int out_size, void* d_ws, size_t ws_size,
                              hipStream_t stream) {
  if (ws_size < (size_t)BLOBB) return;
  P p;
  p.spec   = (const float*)d_in[0];
  p.fw_ih1 = (const float*)d_in[1];  p.fw_hh1 = (const float*)d_in[2];  p.fb1 = (const float*)d_in[3];
  p.fw_ih2 = (const float*)d_in[4];  p.fw_hh2 = (const float*)d_in[5];  p.fb2 = (const float*)d_in[6];
  p.fw_ih3 = (const float*)d_in[7];  p.fw_hh3 = (const float*)d_in[8];  p.fb3 = (const float*)d_in[9];
  p.fw_ih4 = (const float*)d_in[10]; p.fw_hh4 = (const float*)d_in[11]; p.fb4 = (const float*)d_in[12];
  p.bw_ih1 = (const float*)d_in[13]; p.bw_hh1 = (const float*)d_in[14]; p.bb1 = (const float*)d_in[15];
  p.bw_ih2 = (const float*)d_in[16]; p.bw_hh2 = (const float*)d_in[17]; p.bb2 = (const float*)d_in[18];
  p.bw_ih3 = (const float*)d_in[19]; p.bw_hh3 = (const float*)d_in[20]; p.bb3 = (const float*)d_in[21];
  p.bw_ih4 = (const float*)d_in[22]; p.bw_hh4 = (const float*)d_in[23]; p.bb4 = (const float*)d_in[24];
  p.ft12h = (const float*)d_in[25]; p.ft12c = (const float*)d_in[26];
  p.ft23h = (const float*)d_in[27]; p.ft23c = (const float*)d_in[28];
  p.ft34h = (const float*)d_in[29];
  p.bt43h = (const float*)d_in[30]; p.bt43c = (const float*)d_in[31];
  p.bt32h = (const float*)d_in[32]; p.bt32c = (const float*)d_in[33];
  p.bt21h = (const float*)d_in[34]; p.bt21c = (const float*)d_in[35];
  p.out = (float*)d_out;

  char* blob = (char*)d_ws;
  hipLaunchKernelGGL(dsgsf_prep, dim3(8), dim3(256), 0, stream, p, blob);
  int Bn = in_sizes[0] / 128;
  hipLaunchKernelGGL(dsgsf_main, dim3(Bn/64), dim3(512), 0, stream, p, (const char*)blob);
}